// Round 3
// baseline (5037.849 us; speedup 1.0000x reference)
//
#include <hip/hip_runtime.h>

#define B_    32
#define T_    512
#define I_    256
#define H_    512
#define NBLK  32          // 32 blocks; block pb owns 16 fwd-hid + 16 bwd-hid
#define PBF   32          // arrivals per direction flag (all blocks publish both dirs)
#define NT    256
#define NSLOT 4           // h slot rotation (WAR slack only)
#define HPITCH 17         // fp32 LDS h-transpose pitch (odd -> conflict-free)

typedef __attribute__((ext_vector_type(8))) short    short8;
typedef __attribute__((ext_vector_type(4))) float    float4v;

__device__ __forceinline__ unsigned short f2bf(float f) {
    union { float f; unsigned u; } v; v.f = f;
    unsigned r = v.u + 0x7FFFu + ((v.u >> 16) & 1u);   // RTNE
    return (unsigned short)(r >> 16);
}

__device__ __forceinline__ short8 cvt8(const float* p) {
    float4 u = *reinterpret_cast<const float4*>(p);
    float4 v = *reinterpret_cast<const float4*>(p + 4);
    short8 r;
    r[0] = (short)f2bf(u.x); r[1] = (short)f2bf(u.y);
    r[2] = (short)f2bf(u.z); r[3] = (short)f2bf(u.w);
    r[4] = (short)f2bf(v.x); r[5] = (short)f2bf(v.y);
    r[6] = (short)f2bf(v.z); r[7] = (short)f2bf(v.w);
    return r;
}

__device__ __forceinline__ unsigned long long pack4bf(float a, float b, float c, float d) {
    return (unsigned long long)f2bf(a)
         | ((unsigned long long)f2bf(b) << 16)
         | ((unsigned long long)f2bf(c) << 32)
         | ((unsigned long long)f2bf(d) << 48);
}

__device__ __forceinline__ float sigm(float v)  { return 1.0f / (1.0f + __expf(-v)); }
__device__ __forceinline__ float tanhf_(float v){ return 2.0f / (1.0f + __expf(-2.0f * v)) - 1.0f; }

// ---------------- prepass: x[B][T][I] fp32 -> xfrag[T][chunk16][lane64][8] bf16 ----------------
__global__ __launch_bounds__(256) void build_xfrag(const float* __restrict__ x,
                                                   unsigned short* __restrict__ xf) {
    const int t = blockIdx.x, tid = threadIdx.x;
#pragma unroll
    for (int rep = 0; rep < 4; ++rep) {
        const int eidx  = rep * 256 + tid;
        const int chunk = eidx >> 6, lf = eidx & 63;
        const int kstep = chunk >> 1, nh = chunk & 1;
        const int kq = lf >> 4, nm = lf & 15;
        const int b  = nh * 16 + nm;
        const int i0 = kstep * 32 + kq * 8;
        short8 v = cvt8(x + ((size_t)b * T_ + t) * I_ + i0);
        *reinterpret_cast<short8*>(xf + ((size_t)t * 16 + chunk) * 512 + lf * 8) = v;
    }
}

// One LSTM phase (direction D) for timestep t. Token-pasted to keep all state in registers.
#define PHASE(D, TXV, NTXV, C0, C1, WX, WH, BQ)                                              \
  {                                                                                          \
    /* 1. prefetched x regs -> sAX */                                                        \
    _Pragma("unroll")                                                                        \
    for (int c = 0; c < 4; ++c)                                                              \
      *reinterpret_cast<uint4*>(sAX + (w * 4 + c) * 1024 + lane * 16) = xpre[c];             \
    /* 1b. issue next phase's x prefetch (covered by a full phase of compute) */             \
    {                                                                                        \
      const char* nsrc = xfrag_b + ((size_t)(NTXV) * 16 + w * 4) * 1024 + lane * 16;         \
      _Pragma("unroll")                                                                      \
      for (int c = 0; c < 4; ++c)                                                            \
        xpre[c] = *reinterpret_cast<const uint4*>(nsrc + c * 1024);                          \
    }                                                                                        \
    /* 2. wait for h(t-1) of dir D -- flags were set one opposite-phase ago */               \
    if (t > 0 && tid == 0) {                                                                 \
      while (__hip_atomic_load(&bar[(D) * T_ + (t - 1)], __ATOMIC_RELAXED,                   \
                               __HIP_MEMORY_SCOPE_AGENT) < PBF)                              \
        __builtin_amdgcn_s_sleep(1);                                                         \
    }                                                                                        \
    __syncthreads(); /* (A) */                                                               \
    /* 3. issue h-frag loads (agent scope; latency overlapped by x-MFMA) */                  \
    unsigned long long hbuf[16];                                                             \
    if (t > 0) {                                                                             \
      const char* hsrc = hfrag_b + ((size_t)((D) * NSLOT + pslot) * 32 + w * 8) * 1024       \
                       + lane * 16;                                                          \
      _Pragma("unroll")                                                                      \
      for (int c = 0; c < 8; ++c) {                                                          \
        hbuf[2 * c + 0] = __hip_atomic_load((const unsigned long long*)(hsrc + c * 1024),    \
                                            __ATOMIC_RELAXED, __HIP_MEMORY_SCOPE_AGENT);     \
        hbuf[2 * c + 1] = __hip_atomic_load((const unsigned long long*)(hsrc + c * 1024 + 8),\
                                            __ATOMIC_RELAXED, __HIP_MEMORY_SCOPE_AGENT);     \
      }                                                                                      \
    }                                                                                        \
    /* 4. x-MFMA */                                                                          \
    float4v a0 = BQ, a1 = BQ;                                                                \
    _Pragma("unroll")                                                                        \
    for (int kst = 0; kst < 8; ++kst) {                                                      \
      short8 f0 = *reinterpret_cast<const short8*>(sAX + (kst * 2 + 0) * 1024 + lane * 16);  \
      short8 f1 = *reinterpret_cast<const short8*>(sAX + (kst * 2 + 1) * 1024 + lane * 16);  \
      a0 = __builtin_amdgcn_mfma_f32_16x16x32_bf16(WX[kst], f0, a0, 0, 0, 0);                \
      a1 = __builtin_amdgcn_mfma_f32_16x16x32_bf16(WX[kst], f1, a1, 0, 0, 0);                \
    }                                                                                        \
    /* 3b. h frags -> LDS */                                                                 \
    if (t > 0) {                                                                             \
      _Pragma("unroll")                                                                      \
      for (int c = 0; c < 8; ++c) {                                                          \
        char* hdst = sAH + (w * 8 + c) * 1024 + lane * 16;                                   \
        *reinterpret_cast<unsigned long long*>(hdst)     = hbuf[2 * c + 0];                  \
        *reinterpret_cast<unsigned long long*>(hdst + 8) = hbuf[2 * c + 1];                  \
      }                                                                                      \
    }                                                                                        \
    __syncthreads(); /* (B) */                                                               \
    /* 5. h-MFMA */                                                                          \
    if (t > 0) {                                                                             \
      _Pragma("unroll")                                                                      \
      for (int kst = 0; kst < 16; ++kst) {                                                   \
        short8 f0 = *reinterpret_cast<const short8*>(sAH + (kst * 2 + 0) * 1024 + lane * 16);\
        short8 f1 = *reinterpret_cast<const short8*>(sAH + (kst * 2 + 1) * 1024 + lane * 16);\
        a0 = __builtin_amdgcn_mfma_f32_16x16x32_bf16(WH[kst], f0, a0, 0, 0, 0);              \
        a1 = __builtin_amdgcn_mfma_f32_16x16x32_bf16(WH[kst], f1, a1, 0, 0, 0);              \
      }                                                                                      \
    }                                                                                        \
    /* 6. LSTM cell (hid0; batches mA and mA+16) */                                          \
    float h0v, h1v;                                                                          \
    {                                                                                        \
      float iv, fv, gv, ov, cc;                                                              \
      iv = sigm(a0[0]); fv = sigm(a0[1]); gv = tanhf_(a0[2]); ov = sigm(a0[3]);              \
      cc = fv * (C0) + iv * gv; (C0) = cc; h0v = ov * tanhf_(cc);                            \
      iv = sigm(a1[0]); fv = sigm(a1[1]); gv = tanhf_(a1[2]); ov = sigm(a1[3]);              \
      cc = fv * (C1) + iv * gv; (C1) = cc; h1v = ov * tanhf_(cc);                            \
    }                                                                                        \
    /* 7. transpose h through LDS (fp32): sHT[b][hid_local], hid_local = 4w+kqA */           \
    {                                                                                        \
      const int hl = 4 * w + kqA;                                                            \
      sHT[mA * HPITCH + hl]        = h0v;                                                    \
      sHT[(mA + 16) * HPITCH + hl] = h1v;                                                    \
    }                                                                                        \
    __syncthreads(); /* (B2) */                                                              \
    /* 8. publish: 64 lanes, each one 16B frag unit (8 hid x 1 batch) */                     \
    float2 f01, f23, f45, f67;                                                               \
    if (tid < 64) {                                                                          \
      const float* rp = sHT + pub_b * HPITCH + 8 * pub_r8;                                   \
      f01 = *reinterpret_cast<const float2*>(rp + 0);                                        \
      f23 = *reinterpret_cast<const float2*>(rp + 2);                                        \
      f45 = *reinterpret_cast<const float2*>(rp + 4);                                        \
      f67 = *reinterpret_cast<const float2*>(rp + 6);                                        \
      const unsigned long long lo = pack4bf(f01.x, f01.y, f23.x, f23.y);                     \
      const unsigned long long hi = pack4bf(f45.x, f45.y, f67.x, f67.y);                     \
      char* pdst = (char*)hfrag + ((size_t)(((D) * NSLOT + slot) * 32 + pub_chunk)) * 1024   \
                 + pub_lf * 16;                                                              \
      __hip_atomic_store((unsigned long long*)pdst,       lo, __ATOMIC_RELAXED,              \
                         __HIP_MEMORY_SCOPE_AGENT);                                          \
      __hip_atomic_store((unsigned long long*)(pdst + 8), hi, __ATOMIC_RELAXED,              \
                         __HIP_MEMORY_SCOPE_AGENT);                                          \
    }                                                                                        \
    __syncthreads(); /* (C) publishes drained (vmcnt(0) before barrier) */                   \
    /* 9. arrive */                                                                          \
    if (tid == 0)                                                                            \
      __hip_atomic_fetch_add(&bar[(D) * T_ + t], 1u, __ATOMIC_RELAXED,                       \
                             __HIP_MEMORY_SCOPE_AGENT);                                      \
    /* 10. out stores -- off critical path */                                                \
    if (tid < 64) {                                                                          \
      float* op = out + ((size_t)pub_b * T_ + (TXV)) * (2 * H_) + (size_t)(D) * H_           \
                + 16 * pb + 8 * pub_r8;                                                      \
      *reinterpret_cast<float4*>(op + 0) = make_float4(f01.x, f01.y, f23.x, f23.y);          \
      *reinterpret_cast<float4*>(op + 4) = make_float4(f45.x, f45.y, f67.x, f67.y);          \
    }                                                                                        \
  }

// ---------------- main persistent kernel: each block = fwd phase + bwd phase per step ----
__global__ __launch_bounds__(NT, 1) void bilstm_mfma(
    const float* __restrict__ Wih_f, const float* __restrict__ Whh_f, const float* __restrict__ bias_f,
    const float* __restrict__ Wih_b, const float* __restrict__ Whh_b, const float* __restrict__ bias_b,
    float* __restrict__ out, float* __restrict__ ws) {

    __shared__ __align__(16) char  sAX[16 * 1024];      // x B-frags (time-shared fwd/bwd)
    __shared__ __align__(16) char  sAH[32 * 1024];      // h B-frags (time-shared fwd/bwd)
    __shared__ __align__(16) float sHT[B_ * HPITCH];    // fp32 h transpose [b][hid_local 0..15]

    const int tid  = threadIdx.x;
    const int lane = tid & 63;
    const int w    = tid >> 6;
    const int pb   = blockIdx.x;                         // 0..31: owns hid [16pb,16pb+16) per dir

    const char* xfrag_b = (const char*)ws;                                       // 8 MB
    unsigned long long* hfrag = (unsigned long long*)((char*)ws + (size_t)T_ * 16 * 1024);
    const char* hfrag_b = (const char*)hfrag;                                    // 256 KB
    unsigned* bar = (unsigned*)((char*)hfrag + (size_t)2 * NSLOT * 32 * 1024);   // [2][T]

    // ---- one-time: weights -> resident A-fragments (bf16), both directions ----
    const int mA  = lane & 15;
    const int kqA = lane >> 4;
    const int gA  = mA & 3;
    const int gr  = gA * H_ + 16 * pb + 4 * w + (mA >> 2);   // gate-row for this lane's A-frag

    short8 wxF[8], whF[16], wxB[8], whB[16];
#pragma unroll
    for (int kst = 0; kst < 8; ++kst) {
        wxF[kst] = cvt8(Wih_f + (size_t)gr * I_ + kst * 32 + kqA * 8);
        wxB[kst] = cvt8(Wih_b + (size_t)gr * I_ + kst * 32 + kqA * 8);
    }
#pragma unroll
    for (int kst = 0; kst < 16; ++kst) {
        whF[kst] = cvt8(Whh_f + (size_t)gr * H_ + kst * 32 + kqA * 8);
        whB[kst] = cvt8(Whh_b + (size_t)gr * H_ + kst * 32 + kqA * 8);
    }

    const int hid0 = 16 * pb + 4 * w + kqA;              // cell hid for this lane
    float4v bqF, bqB;
#pragma unroll
    for (int g2 = 0; g2 < 4; ++g2) {
        bqF[g2] = bias_f[g2 * H_ + hid0];
        bqB[g2] = bias_b[g2 * H_ + hid0];
    }

    // publisher mapping (tid<64): unit = 8 consecutive hid at fixed batch
    const int pub_b  = tid & 31;
    const int pub_r8 = tid >> 5;                         // 0..1: local hid run 8*r8..8*r8+7
    const unsigned pub_chunk = (unsigned)((pb & ~1) + (pub_b >> 4));
    const unsigned pub_lf    = (unsigned)(((pb & 1) * 2 + pub_r8) * 16 + (pub_b & 15));

    // ---- x prefetch pipeline (1 phase deep): prologue loads fwd t=0 ----
    uint4 xpre[4];
    {
        const char* nsrc = xfrag_b + ((size_t)0 * 16 + w * 4) * 1024 + lane * 16;
#pragma unroll
        for (int c = 0; c < 4; ++c)
            xpre[c] = *reinterpret_cast<const uint4*>(nsrc + c * 1024);
    }

    float cF0 = 0.f, cF1 = 0.f, cB0 = 0.f, cB1 = 0.f;
    __syncthreads();

    for (int t = 0; t < T_; ++t) {
        const int slot  = t & (NSLOT - 1);
        const int pslot = (t - 1) & (NSLOT - 1);
        const int txF   = t;
        const int txB   = T_ - 1 - t;
        const int txNext = (t + 1 < T_) ? (t + 1) : 0;   // next fwd prefetch (clamped)

        // FWD phase: waits on fwd flags set one bwd-phase ago (fully drained)
        PHASE(0, txF, txB, cF0, cF1, wxF, whF, bqF)
        // BWD phase: waits on bwd flags set one fwd-phase ago (fully drained)
        PHASE(1, txB, txNext, cB0, cB1, wxB, whB, bqB)
    }
}

extern "C" void kernel_launch(void* const* d_in, const int* in_sizes, int n_in,
                              void* d_out, int out_size, void* d_ws, size_t ws_size,
                              hipStream_t stream) {
    const float* x     = (const float*)d_in[0];
    const float* Wih_f = (const float*)d_in[1];
    const float* Whh_f = (const float*)d_in[2];
    const float* b_f   = (const float*)d_in[3];
    const float* Wih_b = (const float*)d_in[4];
    const float* Whh_b = (const float*)d_in[5];
    const float* b_b   = (const float*)d_in[6];
    float* out = (float*)d_out;

    const size_t xf_bytes  = (size_t)T_ * 16 * 1024;          // 8 MB
    const size_t hf_bytes  = (size_t)2 * NSLOT * 32 * 1024;   // 256 KB
    const size_t bar_bytes = (size_t)2 * T_ * sizeof(unsigned);

    hipMemsetAsync((char*)d_ws + xf_bytes + hf_bytes, 0, bar_bytes, stream);

    hipLaunchKernelGGL(build_xfrag, dim3(T_), dim3(256), 0, stream,
                       x, (unsigned short*)d_ws);

    hipLaunchKernelGGL(bilstm_mfma, dim3(NBLK), dim3(NT), 0, stream,
                       Wih_f, Whh_f, b_f, Wih_b, Whh_b, b_b, out, (float*)d_ws);
}

// Round 4
// 2749.730 us; speedup vs baseline: 1.8321x; 1.8321x over previous
//
#include <hip/hip_runtime.h>

#define B_    32
#define T_    512
#define I_    256
#define H_    512
#define PB    16          // blocks per direction
#define NBLK  32
#define NT    256
#define NSLOT 4           // h slot rotation (WAR slack only)
#define HPITCH 34         // fp32 LDS h-transpose pitch (2-way banks = free)

typedef __attribute__((ext_vector_type(8))) short  short8;
typedef __attribute__((ext_vector_type(4))) float  float4v;

__device__ __forceinline__ unsigned short f2bf(float f) {
    union { float f; unsigned u; } v; v.f = f;
    unsigned r = v.u + 0x7FFFu + ((v.u >> 16) & 1u);   // RTNE
    return (unsigned short)(r >> 16);
}

__device__ __forceinline__ short8 cvt8(const float* p) {
    float4 u = *reinterpret_cast<const float4*>(p);
    float4 v = *reinterpret_cast<const float4*>(p + 4);
    short8 r;
    r[0] = (short)f2bf(u.x); r[1] = (short)f2bf(u.y);
    r[2] = (short)f2bf(u.z); r[3] = (short)f2bf(u.w);
    r[4] = (short)f2bf(v.x); r[5] = (short)f2bf(v.y);
    r[6] = (short)f2bf(v.z); r[7] = (short)f2bf(v.w);
    return r;
}

__device__ __forceinline__ unsigned long long pack4bf(float a, float b, float c, float d) {
    return (unsigned long long)f2bf(a)
         | ((unsigned long long)f2bf(b) << 16)
         | ((unsigned long long)f2bf(c) << 32)
         | ((unsigned long long)f2bf(d) << 48);
}

__device__ __forceinline__ float sigm(float v)  { return 1.0f / (1.0f + __expf(-v)); }
__device__ __forceinline__ float tanhf_(float v){ return 2.0f / (1.0f + __expf(-2.0f * v)) - 1.0f; }

// 8x 16B L3-coherent loads (bypass L1+L2; same visibility as agent atomic loads).
// Values valid only after an explicit s_waitcnt by the caller (rule #18: follow with sched_barrier).
__device__ __forceinline__ void ld_h8(const char* a, short8* o) {
    const char* b = a + 4096;
    asm volatile(
        "global_load_dwordx4 %0, %[pa], off sc0 sc1\n\t"
        "global_load_dwordx4 %1, %[pa], off offset:1024 sc0 sc1\n\t"
        "global_load_dwordx4 %2, %[pa], off offset:2048 sc0 sc1\n\t"
        "global_load_dwordx4 %3, %[pa], off offset:3072 sc0 sc1\n\t"
        "global_load_dwordx4 %4, %[pb], off sc0 sc1\n\t"
        "global_load_dwordx4 %5, %[pb], off offset:1024 sc0 sc1\n\t"
        "global_load_dwordx4 %6, %[pb], off offset:2048 sc0 sc1\n\t"
        "global_load_dwordx4 %7, %[pb], off offset:3072 sc0 sc1"
        : "=&v"(o[0]), "=&v"(o[1]), "=&v"(o[2]), "=&v"(o[3]),
          "=&v"(o[4]), "=&v"(o[5]), "=&v"(o[6]), "=&v"(o[7])
        : [pa]"v"(a), [pb]"v"(b)
        : "memory");
}

// ---------------- prepass: x[B][T][I] fp32 -> xfrag[T][chunk16][lane64][8] bf16 ----------------
__global__ __launch_bounds__(256) void build_xfrag(const float* __restrict__ x,
                                                   unsigned short* __restrict__ xf) {
    const int t = blockIdx.x, tid = threadIdx.x;
#pragma unroll
    for (int rep = 0; rep < 4; ++rep) {
        const int eidx  = rep * 256 + tid;
        const int chunk = eidx >> 6, lf = eidx & 63;
        const int kstep = chunk >> 1, nh = chunk & 1;
        const int kq = lf >> 4, nm = lf & 15;
        const int b  = nh * 16 + nm;
        const int i0 = kstep * 32 + kq * 8;
        short8 v = cvt8(x + ((size_t)b * T_ + t) * I_ + i0);
        *reinterpret_cast<short8*>(xf + ((size_t)t * 16 + chunk) * 512 + lf * 8) = v;
    }
}

// ---------------- main persistent kernel (32 blocks; r0 exchange protocol verbatim) ----------
__global__ __launch_bounds__(NT, 1) void bilstm_mfma(
    const float* __restrict__ Wih_f, const float* __restrict__ Whh_f, const float* __restrict__ bias_f,
    const float* __restrict__ Wih_b, const float* __restrict__ Whh_b, const float* __restrict__ bias_b,
    float* __restrict__ out, float* __restrict__ ws) {

    __shared__ __align__(16) char  sAX[16 * 1024];      // x B-frags (single buffer; barrier-separated)
    __shared__ __align__(16) float sHT[B_ * HPITCH];    // fp32 h transpose [b][hid_local]

    const int tid  = threadIdx.x;
    const int lane = tid & 63;
    const int w    = tid >> 6;
    const int d    = blockIdx.x & 1;
    const int pb   = blockIdx.x >> 1;

    const char* xfrag_b = (const char*)ws;                                       // 8 MB
    unsigned long long* hfrag = (unsigned long long*)((char*)ws + (size_t)T_ * 16 * 1024);
    const char* hfrag_b = (const char*)hfrag;                                    // 256 KB
    unsigned* bar = (unsigned*)((char*)hfrag + (size_t)2 * NSLOT * 32 * 1024);   // [2][T]

    const float* Wih = d ? Wih_b : Wih_f;
    const float* Whh = d ? Whh_b : Whh_f;
    const float* bia = d ? bias_b : bias_f;

    // ---- one-time: weights -> resident A-fragments (bf16) ----
    const int mA  = lane & 15;
    const int kqA = lane >> 4;
    const int gA  = mA & 3;
    const int gr0 = gA * H_ + 32 * pb + 8 * w + (mA >> 2);
    const int gr1 = gr0 + 4;

    short8 wx0[8], wx1[8], wh0[16], wh1[16];
#pragma unroll
    for (int kst = 0; kst < 8; ++kst) {
        wx0[kst] = cvt8(Wih + (size_t)gr0 * I_ + kst * 32 + kqA * 8);
        wx1[kst] = cvt8(Wih + (size_t)gr1 * I_ + kst * 32 + kqA * 8);
    }
#pragma unroll
    for (int kst = 0; kst < 16; ++kst) {
        wh0[kst] = cvt8(Whh + (size_t)gr0 * H_ + kst * 32 + kqA * 8);
        wh1[kst] = cvt8(Whh + (size_t)gr1 * H_ + kst * 32 + kqA * 8);
    }

    const int hid0 = 32 * pb + 8 * w + kqA;
    float4v bq0, bq1;
#pragma unroll
    for (int g = 0; g < 4; ++g) {
        bq0[g] = bia[g * H_ + hid0];
        bq1[g] = bia[g * H_ + hid0 + 4];
    }

    // publisher mapping (tid<128): unit = 8 consecutive hid at fixed batch
    const int pub_b  = tid & 31;
    const int pub_r8 = tid >> 5;
    const unsigned pub_chunkL = pb * 2 + (pub_b >> 4);
    const unsigned pub_lf     = pub_r8 * 16 + (pub_b & 15);

    // ---- prologue: stage x(tx(0)) -> sAX, compute xacc(0); prefetch x(tx(1)) -> regs ----
    {
        const int tx0 = d ? (T_ - 1) : 0;
        const char* src = xfrag_b + ((size_t)tx0 * 16 + w * 4) * 1024 + lane * 16;
#pragma unroll
        for (int c = 0; c < 4; ++c) {
            uint4 v = *reinterpret_cast<const uint4*>(src + c * 1024);
            *reinterpret_cast<uint4*>(sAX + (w * 4 + c) * 1024 + lane * 16) = v;
        }
    }
    __syncthreads();

    float4v xa00 = bq0, xa01 = bq0, xa10 = bq1, xa11 = bq1;
#pragma unroll
    for (int kst = 0; kst < 8; ++kst) {
        short8 f0 = *reinterpret_cast<const short8*>(sAX + (kst * 2 + 0) * 1024 + lane * 16);
        short8 f1 = *reinterpret_cast<const short8*>(sAX + (kst * 2 + 1) * 1024 + lane * 16);
        xa00 = __builtin_amdgcn_mfma_f32_16x16x32_bf16(wx0[kst], f0, xa00, 0, 0, 0);
        xa01 = __builtin_amdgcn_mfma_f32_16x16x32_bf16(wx0[kst], f1, xa01, 0, 0, 0);
        xa10 = __builtin_amdgcn_mfma_f32_16x16x32_bf16(wx1[kst], f0, xa10, 0, 0, 0);
        xa11 = __builtin_amdgcn_mfma_f32_16x16x32_bf16(wx1[kst], f1, xa11, 0, 0, 0);
    }

    uint4 xpre[4];
    {
        const int tx1 = d ? (T_ - 2) : 1;
        const char* src = xfrag_b + ((size_t)tx1 * 16 + w * 4) * 1024 + lane * 16;
#pragma unroll
        for (int c = 0; c < 4; ++c)
            xpre[c] = *reinterpret_cast<const uint4*>(src + c * 1024);
    }

    float c00 = 0.f, c01 = 0.f, c10 = 0.f, c11 = 0.f;

    for (int t = 0; t < T_; ++t) {
        const int tx    = d ? (T_ - 1 - t) : t;
        const int slot  = t & (NSLOT - 1);
        const int pslot = (t - 1) & (NSLOT - 1);

        // ---- 1. wait for h(t-1) ----
        if (t > 0 && tid == 0) {
            while (__hip_atomic_load(&bar[d * T_ + (t - 1)], __ATOMIC_RELAXED,
                                     __HIP_MEMORY_SCOPE_AGENT) < PB)
                __builtin_amdgcn_s_sleep(1);
        }
        __syncthreads();   // (A)  [also: prev iter's sAX reads complete before restage]

        // acc starts from precomputed x-projection
        float4v a00 = xa00, a01 = xa01, a10 = xa10, a11 = xa11;

        // ---- 2. issue ALL 32 h-frag loads direct from L3 (no LDS round-trip) ----
        short8 hf[32];
        if (t > 0) {
            const char* hsrc = hfrag_b + ((size_t)(d * NSLOT + pslot) * 32) * 1024 + lane * 16;
            ld_h8(hsrc,          hf + 0);
            ld_h8(hsrc +  8192,  hf + 8);
            ld_h8(hsrc + 16384,  hf + 16);
            ld_h8(hsrc + 24576,  hf + 24);
        }

        // ---- 3. stage x(t+1) regs -> sAX (overlaps h-load latency; lgkm only) ----
        if (t + 1 < T_) {
#pragma unroll
            for (int c = 0; c < 4; ++c)
                *reinterpret_cast<uint4*>(sAX + (w * 4 + c) * 1024 + lane * 16) = xpre[c];
        }

        // ---- 4. h-MFMA, streamed: first half after vmcnt(16), rest after vmcnt(0) ----
        if (t > 0) {
            __builtin_amdgcn_sched_barrier(0);
            asm volatile("s_waitcnt vmcnt(16)" ::: "memory");
            __builtin_amdgcn_sched_barrier(0);
#pragma unroll
            for (int kst = 0; kst < 8; ++kst) {
                short8 f0 = hf[2 * kst + 0];
                short8 f1 = hf[2 * kst + 1];
                a00 = __builtin_amdgcn_mfma_f32_16x16x32_bf16(wh0[kst], f0, a00, 0, 0, 0);
                a01 = __builtin_amdgcn_mfma_f32_16x16x32_bf16(wh0[kst], f1, a01, 0, 0, 0);
                a10 = __builtin_amdgcn_mfma_f32_16x16x32_bf16(wh1[kst], f0, a10, 0, 0, 0);
                a11 = __builtin_amdgcn_mfma_f32_16x16x32_bf16(wh1[kst], f1, a11, 0, 0, 0);
            }
            __builtin_amdgcn_sched_barrier(0);
            asm volatile("s_waitcnt vmcnt(0)" ::: "memory");
            __builtin_amdgcn_sched_barrier(0);
#pragma unroll
            for (int kst = 8; kst < 16; ++kst) {
                short8 f0 = hf[2 * kst + 0];
                short8 f1 = hf[2 * kst + 1];
                a00 = __builtin_amdgcn_mfma_f32_16x16x32_bf16(wh0[kst], f0, a00, 0, 0, 0);
                a01 = __builtin_amdgcn_mfma_f32_16x16x32_bf16(wh0[kst], f1, a01, 0, 0, 0);
                a10 = __builtin_amdgcn_mfma_f32_16x16x32_bf16(wh1[kst], f0, a10, 0, 0, 0);
                a11 = __builtin_amdgcn_mfma_f32_16x16x32_bf16(wh1[kst], f1, a11, 0, 0, 0);
            }
        }

        // ---- 5. LSTM cell ----
        float h00, h01, h10, h11;
        {
            float iv, fv, gv, ov, c;
            iv = sigm(a00[0]); fv = sigm(a00[1]); gv = tanhf_(a00[2]); ov = sigm(a00[3]);
            c = fv * c00 + iv * gv; c00 = c; h00 = ov * tanhf_(c);
            iv = sigm(a01[0]); fv = sigm(a01[1]); gv = tanhf_(a01[2]); ov = sigm(a01[3]);
            c = fv * c01 + iv * gv; c01 = c; h01 = ov * tanhf_(c);
            iv = sigm(a10[0]); fv = sigm(a10[1]); gv = tanhf_(a10[2]); ov = sigm(a10[3]);
            c = fv * c10 + iv * gv; c10 = c; h10 = ov * tanhf_(c);
            iv = sigm(a11[0]); fv = sigm(a11[1]); gv = tanhf_(a11[2]); ov = sigm(a11[3]);
            c = fv * c11 + iv * gv; c11 = c; h11 = ov * tanhf_(c);
        }

        // ---- 6. transpose h through LDS (fp32): sHT[b][hid_local] ----
        {
            const int hl = 8 * w + kqA;
            const int bn = mA;
            sHT[(bn)      * HPITCH + hl]     = h00;
            sHT[(bn + 16) * HPITCH + hl]     = h01;
            sHT[(bn)      * HPITCH + hl + 4] = h10;
            sHT[(bn + 16) * HPITCH + hl + 4] = h11;
        }
        __syncthreads();   // (B2) sHT complete

        // ---- 7. publish: 128 lanes, each one 16 B frag unit (2x u64 agent stores) ----
        float2 f01, f23, f45, f67;
        if (tid < 128) {
            const float* rp = sHT + pub_b * HPITCH + 8 * pub_r8;
            f01 = *reinterpret_cast<const float2*>(rp + 0);
            f23 = *reinterpret_cast<const float2*>(rp + 2);
            f45 = *reinterpret_cast<const float2*>(rp + 4);
            f67 = *reinterpret_cast<const float2*>(rp + 6);
            const unsigned long long lo = pack4bf(f01.x, f01.y, f23.x, f23.y);
            const unsigned long long hi = pack4bf(f45.x, f45.y, f67.x, f67.y);
            char* dst = (char*)hfrag + ((size_t)((d * NSLOT + slot) * 32 + pub_chunkL)) * 1024
                      + pub_lf * 16;
            __hip_atomic_store((unsigned long long*)dst,       lo, __ATOMIC_RELAXED, __HIP_MEMORY_SCOPE_AGENT);
            __hip_atomic_store((unsigned long long*)(dst + 8), hi, __ATOMIC_RELAXED, __HIP_MEMORY_SCOPE_AGENT);
        }
        __syncthreads();   // (C) publishes drained (vmcnt(0) before barrier)

        // ---- 8. arrive ----
        if (tid == 0)
            __hip_atomic_fetch_add(&bar[d * T_ + t], 1u, __ATOMIC_RELAXED,
                                   __HIP_MEMORY_SCOPE_AGENT);

        // ---- 9. out stores — off critical path ----
        if (tid < 128) {
            float* op = out + ((size_t)pub_b * T_ + tx) * (2 * H_) + (size_t)d * H_
                      + 32 * pb + 8 * pub_r8;
            *reinterpret_cast<float4*>(op + 0) = make_float4(f01.x, f01.y, f23.x, f23.y);
            *reinterpret_cast<float4*>(op + 4) = make_float4(f45.x, f45.y, f67.x, f67.y);
        }

        // ---- 10. x-MFMA for t+1 (runs in the detect window; sAX staged at (3)) ----
        if (t + 1 < T_) {
            xa00 = bq0; xa01 = bq0; xa10 = bq1; xa11 = bq1;
#pragma unroll
            for (int kst = 0; kst < 8; ++kst) {
                short8 f0 = *reinterpret_cast<const short8*>(sAX + (kst * 2 + 0) * 1024 + lane * 16);
                short8 f1 = *reinterpret_cast<const short8*>(sAX + (kst * 2 + 1) * 1024 + lane * 16);
                xa00 = __builtin_amdgcn_mfma_f32_16x16x32_bf16(wx0[kst], f0, xa00, 0, 0, 0);
                xa01 = __builtin_amdgcn_mfma_f32_16x16x32_bf16(wx0[kst], f1, xa01, 0, 0, 0);
                xa10 = __builtin_amdgcn_mfma_f32_16x16x32_bf16(wx1[kst], f0, xa10, 0, 0, 0);
                xa11 = __builtin_amdgcn_mfma_f32_16x16x32_bf16(wx1[kst], f1, xa11, 0, 0, 0);
            }
        }

        // ---- 11. prefetch x(t+2) -> regs (consumed at (3) next iter; full-step latency) ----
        if (t + 2 < T_) {
            const int txn2 = d ? (T_ - 3 - t) : (t + 2);
            const char* src = xfrag_b + ((size_t)txn2 * 16 + w * 4) * 1024 + lane * 16;
#pragma unroll
            for (int c = 0; c < 4; ++c)
                xpre[c] = *reinterpret_cast<const uint4*>(src + c * 1024);
        }
    }
}

extern "C" void kernel_launch(void* const* d_in, const int* in_sizes, int n_in,
                              void* d_out, int out_size, void* d_ws, size_t ws_size,
                              hipStream_t stream) {
    const float* x     = (const float*)d_in[0];
    const float* Wih_f = (const float*)d_in[1];
    const float* Whh_f = (const float*)d_in[2];
    const float* b_f   = (const float*)d_in[3];
    const float* Wih_b = (const float*)d_in[4];
    const float* Whh_b = (const float*)d_in[5];
    const float* b_b   = (const float*)d_in[6];
    float* out = (float*)d_out;

    const size_t xf_bytes  = (size_t)T_ * 16 * 1024;          // 8 MB
    const size_t hf_bytes  = (size_t)2 * NSLOT * 32 * 1024;   // 256 KB
    const size_t bar_bytes = (size_t)2 * T_ * sizeof(unsigned);

    hipMemsetAsync((char*)d_ws + xf_bytes + hf_bytes, 0, bar_bytes, stream);

    hipLaunchKernelGGL(build_xfrag, dim3(T_), dim3(256), 0, stream,
                       x, (unsigned short*)d_ws);

    hipLaunchKernelGGL(bilstm_mfma, dim3(NBLK), dim3(NT), 0, stream,
                       Wih_f, Whh_f, b_f, Wih_b, Whh_b, b_b, out, (float*)d_ws);
}

// Round 5
// 2467.939 us; speedup vs baseline: 2.0413x; 1.1142x over previous
//
#include <hip/hip_runtime.h>

#define B_    32
#define T_    512
#define I_    256
#define H_    512
#define PB    16          // blocks per direction
#define NBLK  32
#define NT    256
#define NSLOT 4           // h slot rotation (WAR slack only)
#define HPITCH 34         // fp32 LDS h-transpose pitch (2-way banks = free)

typedef __attribute__((ext_vector_type(8))) short  short8;
typedef __attribute__((ext_vector_type(4))) float  float4v;

__device__ __forceinline__ unsigned short f2bf(float f) {
    union { float f; unsigned u; } v; v.f = f;
    unsigned r = v.u + 0x7FFFu + ((v.u >> 16) & 1u);   // RTNE
    return (unsigned short)(r >> 16);
}

__device__ __forceinline__ short8 cvt8(const float* p) {
    float4 u = *reinterpret_cast<const float4*>(p);
    float4 v = *reinterpret_cast<const float4*>(p + 4);
    short8 r;
    r[0] = (short)f2bf(u.x); r[1] = (short)f2bf(u.y);
    r[2] = (short)f2bf(u.z); r[3] = (short)f2bf(u.w);
    r[4] = (short)f2bf(v.x); r[5] = (short)f2bf(v.y);
    r[6] = (short)f2bf(v.z); r[7] = (short)f2bf(v.w);
    return r;
}

__device__ __forceinline__ unsigned long long pack4bf(float a, float b, float c, float d) {
    return (unsigned long long)f2bf(a)
         | ((unsigned long long)f2bf(b) << 16)
         | ((unsigned long long)f2bf(c) << 32)
         | ((unsigned long long)f2bf(d) << 48);
}

__device__ __forceinline__ float sigm(float v)  { return 1.0f / (1.0f + __expf(-v)); }
__device__ __forceinline__ float tanhf_(float v){ return 2.0f / (1.0f + __expf(-2.0f * v)) - 1.0f; }

// ---------------- prepass: x[B][T][I] fp32 -> xfrag[T][chunk16][lane64][8] bf16 ----------------
__global__ __launch_bounds__(256) void build_xfrag(const float* __restrict__ x,
                                                   unsigned short* __restrict__ xf) {
    const int t = blockIdx.x, tid = threadIdx.x;
#pragma unroll
    for (int rep = 0; rep < 4; ++rep) {
        const int eidx  = rep * 256 + tid;
        const int chunk = eidx >> 6, lf = eidx & 63;
        const int kstep = chunk >> 1, nh = chunk & 1;
        const int kq = lf >> 4, nm = lf & 15;
        const int b  = nh * 16 + nm;
        const int i0 = kstep * 32 + kq * 8;
        short8 v = cvt8(x + ((size_t)b * T_ + t) * I_ + i0);
        *reinterpret_cast<short8*>(xf + ((size_t)t * 16 + chunk) * 512 + lf * 8) = v;
    }
}

// ---------------- main persistent kernel (r0 h-chain + post-arrive shadow x-path) ----------
__global__ __launch_bounds__(NT, 1) void bilstm_mfma(
    const float* __restrict__ Wih_f, const float* __restrict__ Whh_f, const float* __restrict__ bias_f,
    const float* __restrict__ Wih_b, const float* __restrict__ Whh_b, const float* __restrict__ bias_b,
    float* __restrict__ out, float* __restrict__ ws) {

    __shared__ __align__(16) char  sAX[16 * 1024];      // x B-frags
    __shared__ __align__(16) char  sAH[32 * 1024];      // h B-frags
    __shared__ __align__(16) float sHT[B_ * HPITCH];    // fp32 h transpose [b][hid_local]

    const int tid  = threadIdx.x;
    const int lane = tid & 63;
    const int w    = tid >> 6;
    const int d    = blockIdx.x & 1;
    const int pb   = blockIdx.x >> 1;

    const char* xfrag_b = (const char*)ws;                                       // 8 MB
    unsigned long long* hfrag = (unsigned long long*)((char*)ws + (size_t)T_ * 16 * 1024);
    const char* hfrag_b = (const char*)hfrag;                                    // 256 KB
    unsigned* bar = (unsigned*)((char*)hfrag + (size_t)2 * NSLOT * 32 * 1024);   // [2][T]

    const float* Wih = d ? Wih_b : Wih_f;
    const float* Whh = d ? Whh_b : Whh_f;
    const float* bia = d ? bias_b : bias_f;

    // ---- one-time: weights -> resident A-fragments (bf16) ----
    const int mA  = lane & 15;
    const int kqA = lane >> 4;
    const int gA  = mA & 3;
    const int gr0 = gA * H_ + 32 * pb + 8 * w + (mA >> 2);
    const int gr1 = gr0 + 4;

    short8 wx0[8], wx1[8], wh0[16], wh1[16];
#pragma unroll
    for (int kst = 0; kst < 8; ++kst) {
        wx0[kst] = cvt8(Wih + (size_t)gr0 * I_ + kst * 32 + kqA * 8);
        wx1[kst] = cvt8(Wih + (size_t)gr1 * I_ + kst * 32 + kqA * 8);
    }
#pragma unroll
    for (int kst = 0; kst < 16; ++kst) {
        wh0[kst] = cvt8(Whh + (size_t)gr0 * H_ + kst * 32 + kqA * 8);
        wh1[kst] = cvt8(Whh + (size_t)gr1 * H_ + kst * 32 + kqA * 8);
    }

    const int hid0 = 32 * pb + 8 * w + kqA;
    float4v bq0, bq1;
#pragma unroll
    for (int g = 0; g < 4; ++g) {
        bq0[g] = bia[g * H_ + hid0];
        bq1[g] = bia[g * H_ + hid0 + 4];
    }

    // publisher mapping (tid<128): unit = 8 consecutive hid at fixed batch
    const int pub_b  = tid & 31;
    const int pub_r8 = tid >> 5;
    const unsigned pub_chunkL = pb * 2 + (pub_b >> 4);
    const unsigned pub_lf     = pub_r8 * 16 + (pub_b & 15);

    // ---- prologue: stage x(tx(0)) -> sAX, compute xa(0); prefetch x(tx(1)) -> regs ----
    {
        const int tx0 = d ? (T_ - 1) : 0;
        const char* src = xfrag_b + ((size_t)tx0 * 16 + w * 4) * 1024 + lane * 16;
#pragma unroll
        for (int c = 0; c < 4; ++c) {
            uint4 v = *reinterpret_cast<const uint4*>(src + c * 1024);
            *reinterpret_cast<uint4*>(sAX + (w * 4 + c) * 1024 + lane * 16) = v;
        }
    }
    __syncthreads();

    float4v xa00 = bq0, xa01 = bq0, xa10 = bq1, xa11 = bq1;
#pragma unroll
    for (int kst = 0; kst < 8; ++kst) {
        short8 f0 = *reinterpret_cast<const short8*>(sAX + (kst * 2 + 0) * 1024 + lane * 16);
        short8 f1 = *reinterpret_cast<const short8*>(sAX + (kst * 2 + 1) * 1024 + lane * 16);
        xa00 = __builtin_amdgcn_mfma_f32_16x16x32_bf16(wx0[kst], f0, xa00, 0, 0, 0);
        xa01 = __builtin_amdgcn_mfma_f32_16x16x32_bf16(wx0[kst], f1, xa01, 0, 0, 0);
        xa10 = __builtin_amdgcn_mfma_f32_16x16x32_bf16(wx1[kst], f0, xa10, 0, 0, 0);
        xa11 = __builtin_amdgcn_mfma_f32_16x16x32_bf16(wx1[kst], f1, xa11, 0, 0, 0);
    }

    uint4 xpre[4];
    {
        const int tx1 = d ? (T_ - 2) : 1;
        const char* src = xfrag_b + ((size_t)tx1 * 16 + w * 4) * 1024 + lane * 16;
#pragma unroll
        for (int c = 0; c < 4; ++c)
            xpre[c] = *reinterpret_cast<const uint4*>(src + c * 1024);
    }

    float c00 = 0.f, c01 = 0.f, c10 = 0.f, c11 = 0.f;

    for (int t = 0; t < T_; ++t) {
        const int tx    = d ? (T_ - 1 - t) : t;
        const int slot  = t & (NSLOT - 1);
        const int pslot = (t - 1) & (NSLOT - 1);

        // ---- 1. wait for h(t-1) ----
        if (t > 0 && tid == 0) {
            while (__hip_atomic_load(&bar[d * T_ + (t - 1)], __ATOMIC_RELAXED,
                                     __HIP_MEMORY_SCOPE_AGENT) < PB)
                __builtin_amdgcn_s_sleep(1);
        }
        __syncthreads();   // (A)

        // ---- 2. h-frag loads: per-wave 8KB slice (r0-identical) ----
        unsigned long long hbuf[16];
        if (t > 0) {
            const char* src = hfrag_b + ((size_t)(d * NSLOT + pslot) * 32 + w * 8) * 1024 + lane * 16;
#pragma unroll
            for (int c = 0; c < 8; ++c) {
                hbuf[2 * c + 0] = __hip_atomic_load((const unsigned long long*)(src + c * 1024),
                                                    __ATOMIC_RELAXED, __HIP_MEMORY_SCOPE_AGENT);
                hbuf[2 * c + 1] = __hip_atomic_load((const unsigned long long*)(src + c * 1024 + 8),
                                                    __ATOMIC_RELAXED, __HIP_MEMORY_SCOPE_AGENT);
            }
            // ---- 3. h frags -> LDS ----
#pragma unroll
            for (int c = 0; c < 8; ++c) {
                char* dst = sAH + (w * 8 + c) * 1024 + lane * 16;
                *reinterpret_cast<unsigned long long*>(dst)     = hbuf[2 * c + 0];
                *reinterpret_cast<unsigned long long*>(dst + 8) = hbuf[2 * c + 1];
            }
        }
        __syncthreads();   // (B)

        // acc starts from precomputed x-projection (bias included)
        float4v a00 = xa00, a01 = xa01, a10 = xa10, a11 = xa11;

        // ---- 4. h-MFMA from LDS ----
        if (t > 0) {
#pragma unroll
            for (int kst = 0; kst < 16; ++kst) {
                short8 f0 = *reinterpret_cast<const short8*>(sAH + (kst * 2 + 0) * 1024 + lane * 16);
                short8 f1 = *reinterpret_cast<const short8*>(sAH + (kst * 2 + 1) * 1024 + lane * 16);
                a00 = __builtin_amdgcn_mfma_f32_16x16x32_bf16(wh0[kst], f0, a00, 0, 0, 0);
                a01 = __builtin_amdgcn_mfma_f32_16x16x32_bf16(wh0[kst], f1, a01, 0, 0, 0);
                a10 = __builtin_amdgcn_mfma_f32_16x16x32_bf16(wh1[kst], f0, a10, 0, 0, 0);
                a11 = __builtin_amdgcn_mfma_f32_16x16x32_bf16(wh1[kst], f1, a11, 0, 0, 0);
            }
        }

        // ---- 5. LSTM cell ----
        float h00, h01, h10, h11;
        {
            float iv, fv, gv, ov, c;
            iv = sigm(a00[0]); fv = sigm(a00[1]); gv = tanhf_(a00[2]); ov = sigm(a00[3]);
            c = fv * c00 + iv * gv; c00 = c; h00 = ov * tanhf_(c);
            iv = sigm(a01[0]); fv = sigm(a01[1]); gv = tanhf_(a01[2]); ov = sigm(a01[3]);
            c = fv * c01 + iv * gv; c01 = c; h01 = ov * tanhf_(c);
            iv = sigm(a10[0]); fv = sigm(a10[1]); gv = tanhf_(a10[2]); ov = sigm(a10[3]);
            c = fv * c10 + iv * gv; c10 = c; h10 = ov * tanhf_(c);
            iv = sigm(a11[0]); fv = sigm(a11[1]); gv = tanhf_(a11[2]); ov = sigm(a11[3]);
            c = fv * c11 + iv * gv; c11 = c; h11 = ov * tanhf_(c);
        }

        // ---- 6. transpose h through LDS (fp32): sHT[b][hid_local] ----
        {
            const int hl = 8 * w + kqA;
            const int bn = mA;
            sHT[(bn)      * HPITCH + hl]     = h00;
            sHT[(bn + 16) * HPITCH + hl]     = h01;
            sHT[(bn)      * HPITCH + hl + 4] = h10;
            sHT[(bn + 16) * HPITCH + hl + 4] = h11;
        }
        __syncthreads();   // (B2) sHT complete

        // ---- 7. publish: 128 lanes, each one 16 B frag unit (2x u64 agent stores) ----
        float2 f01, f23, f45, f67;
        if (tid < 128) {
            const float* rp = sHT + pub_b * HPITCH + 8 * pub_r8;
            f01 = *reinterpret_cast<const float2*>(rp + 0);
            f23 = *reinterpret_cast<const float2*>(rp + 2);
            f45 = *reinterpret_cast<const float2*>(rp + 4);
            f67 = *reinterpret_cast<const float2*>(rp + 6);
            const unsigned long long lo = pack4bf(f01.x, f01.y, f23.x, f23.y);
            const unsigned long long hi = pack4bf(f45.x, f45.y, f67.x, f67.y);
            char* dst = (char*)hfrag + ((size_t)((d * NSLOT + slot) * 32 + pub_chunkL)) * 1024
                      + pub_lf * 16;
            __hip_atomic_store((unsigned long long*)dst,       lo, __ATOMIC_RELAXED, __HIP_MEMORY_SCOPE_AGENT);
            __hip_atomic_store((unsigned long long*)(dst + 8), hi, __ATOMIC_RELAXED, __HIP_MEMORY_SCOPE_AGENT);
        }
        __syncthreads();   // (C) publishes drained (vmcnt(0) before barrier)

        // ---- 8. arrive ----
        if (tid == 0)
            __hip_atomic_fetch_add(&bar[d * T_ + t], 1u, __ATOMIC_RELAXED,
                                   __HIP_MEMORY_SCOPE_AGENT);

        // ================= shadow section (overlaps other blocks + flag propagation) =========
        // ---- 9. out stores (fp32) ----
        if (tid < 128) {
            float* op = out + ((size_t)pub_b * T_ + tx) * (2 * H_) + (size_t)d * H_
                      + 32 * pb + 8 * pub_r8;
            *reinterpret_cast<float4*>(op + 0) = make_float4(f01.x, f01.y, f23.x, f23.y);
            *reinterpret_cast<float4*>(op + 4) = make_float4(f45.x, f45.y, f67.x, f67.y);
        }

        if (t + 1 < T_) {
            // ---- 10. stage x(t+1) from prefetched regs ----
#pragma unroll
            for (int c = 0; c < 4; ++c)
                *reinterpret_cast<uint4*>(sAX + (w * 4 + c) * 1024 + lane * 16) = xpre[c];

            // ---- 11. prefetch x(t+2) -> regs (drained at (D); full shadow+chain latency) ----
            if (t + 2 < T_) {
                const int txn2 = d ? (T_ - 3 - t) : (t + 2);
                const char* src = xfrag_b + ((size_t)txn2 * 16 + w * 4) * 1024 + lane * 16;
#pragma unroll
                for (int c = 0; c < 4; ++c)
                    xpre[c] = *reinterpret_cast<const uint4*>(src + c * 1024);
            }
            __syncthreads();   // (D) sAX staged (in shadow; also drains out stores)

            // ---- 12. x-MFMA for t+1 ----
            xa00 = bq0; xa01 = bq0; xa10 = bq1; xa11 = bq1;
#pragma unroll
            for (int kst = 0; kst < 8; ++kst) {
                short8 f0 = *reinterpret_cast<const short8*>(sAX + (kst * 2 + 0) * 1024 + lane * 16);
                short8 f1 = *reinterpret_cast<const short8*>(sAX + (kst * 2 + 1) * 1024 + lane * 16);
                xa00 = __builtin_amdgcn_mfma_f32_16x16x32_bf16(wx0[kst], f0, xa00, 0, 0, 0);
                xa01 = __builtin_amdgcn_mfma_f32_16x16x32_bf16(wx0[kst], f1, xa01, 0, 0, 0);
                xa10 = __builtin_amdgcn_mfma_f32_16x16x32_bf16(wx1[kst], f0, xa10, 0, 0, 0);
                xa11 = __builtin_amdgcn_mfma_f32_16x16x32_bf16(wx1[kst], f1, xa11, 0, 0, 0);
            }
        }
    }
}

extern "C" void kernel_launch(void* const* d_in, const int* in_sizes, int n_in,
                              void* d_out, int out_size, void* d_ws, size_t ws_size,
                              hipStream_t stream) {
    const float* x     = (const float*)d_in[0];
    const float* Wih_f = (const float*)d_in[1];
    const float* Whh_f = (const float*)d_in[2];
    const float* b_f   = (const float*)d_in[3];
    const float* Wih_b = (const float*)d_in[4];
    const float* Whh_b = (const float*)d_in[5];
    const float* b_b   = (const float*)d_in[6];
    float* out = (float*)d_out;

    const size_t xf_bytes  = (size_t)T_ * 16 * 1024;          // 8 MB
    const size_t hf_bytes  = (size_t)2 * NSLOT * 32 * 1024;   // 256 KB
    const size_t bar_bytes = (size_t)2 * T_ * sizeof(unsigned);

    hipMemsetAsync((char*)d_ws + xf_bytes + hf_bytes, 0, bar_bytes, stream);

    hipLaunchKernelGGL(build_xfrag, dim3(T_), dim3(256), 0, stream,
                       x, (unsigned short*)d_ws);

    hipLaunchKernelGGL(bilstm_mfma, dim3(NBLK), dim3(NT), 0, stream,
                       Wih_f, Whh_f, b_f, Wih_b, Whh_b, b_b, out, (float*)d_ws);
}